// Round 1
// baseline (1151.034 us; speedup 1.0000x reference)
//
#include <hip/hip_runtime.h>
#include <cstdint>
#include <cstddef>

#define HIDN 2048
#define NROWS 4096   // B*S
#define FFND 8192
#define SEQ 2048
#define QKVN 6144    // packed q|k|v row width

typedef __attribute__((ext_vector_type(8))) __bf16 bf16x8;
typedef __attribute__((ext_vector_type(4))) float f32x4;

__device__ __forceinline__ unsigned short f2b(float f) {
    union { float f; unsigned u; } v; v.f = f;
    unsigned r = v.u + 0x7fffu + ((v.u >> 16) & 1u);
    return (unsigned short)(r >> 16);
}
__device__ __forceinline__ float b2f(unsigned short h) {
    union { unsigned u; float f; } v; v.u = ((unsigned)h) << 16; return v.f;
}
__device__ __forceinline__ void gload16(const void* g, void* lds) {
    __builtin_amdgcn_global_load_lds(
        (const __attribute__((address_space(1))) void*)g,
        (__attribute__((address_space(3))) void*)lds, 16, 0, 0);
}

// ---------------- merged fp32 -> bf16 weight convert (dst contiguous in ws) ----------------
__global__ __launch_bounds__(256) void convall_kernel(
    const float* __restrict__ s0, const float* __restrict__ s1,
    const float* __restrict__ s2, const float* __restrict__ s3,
    const float* __restrict__ s4, const float* __restrict__ s5,
    const float* __restrict__ s6, unsigned short* __restrict__ dst) {
    const int M1 = 1 << 20;
    int i = blockIdx.x * 256 + threadIdx.x;   // < 16M guaranteed by grid
    const float* src; int rel;
    if      (i <  1 * M1) { src = s0; rel = i;          }
    else if (i <  2 * M1) { src = s1; rel = i - 1 * M1; }
    else if (i <  3 * M1) { src = s2; rel = i - 2 * M1; }
    else if (i <  4 * M1) { src = s3; rel = i - 3 * M1; }
    else if (i <  8 * M1) { src = s4; rel = i - 4 * M1; }
    else if (i < 12 * M1) { src = s5; rel = i - 8 * M1; }
    else                  { src = s6; rel = i - 12 * M1; }
    float4 v = ((const float4*)src)[rel];
    ushort4 o;
    o.x = f2b(v.x); o.y = f2b(v.y); o.z = f2b(v.z); o.w = f2b(v.w);
    ((ushort4*)dst)[i] = o;
}

// ---------------- LayerNorm: fp32 in -> bf16 out, one block per 2048-row ----------------
__global__ __launch_bounds__(256) void ln_kernel(const float* __restrict__ x,
                                                 const float* __restrict__ w,
                                                 const float* __restrict__ b,
                                                 unsigned short* __restrict__ out) {
    int row = blockIdx.x, tid = threadIdx.x;
    const float4* xr = (const float4*)(x + (size_t)row * HIDN);
    float4 a0 = xr[tid], a1 = xr[tid + 256];
    float s  = a0.x + a0.y + a0.z + a0.w + a1.x + a1.y + a1.z + a1.w;
    float s2 = a0.x*a0.x + a0.y*a0.y + a0.z*a0.z + a0.w*a0.w
             + a1.x*a1.x + a1.y*a1.y + a1.z*a1.z + a1.w*a1.w;
#pragma unroll
    for (int i = 1; i < 64; i <<= 1) { s += __shfl_xor(s, i); s2 += __shfl_xor(s2, i); }
    __shared__ float red[8];
    if ((tid & 63) == 0) { red[tid >> 6] = s; red[4 + (tid >> 6)] = s2; }
    __syncthreads();
    s  = red[0] + red[1] + red[2] + red[3];
    s2 = red[4] + red[5] + red[6] + red[7];
    float mu  = s * (1.0f / HIDN);
    float var = s2 * (1.0f / HIDN) - mu * mu;
    float rstd = rsqrtf(var + 1e-5f);
    const float4* wv = (const float4*)w;
    const float4* bv = (const float4*)b;
    float4 w0 = wv[tid], w1 = wv[tid + 256], b0 = bv[tid], b1 = bv[tid + 256];
    ushort4 o0, o1;
    o0.x = f2b((a0.x - mu) * rstd * w0.x + b0.x);
    o0.y = f2b((a0.y - mu) * rstd * w0.y + b0.y);
    o0.z = f2b((a0.z - mu) * rstd * w0.z + b0.z);
    o0.w = f2b((a0.w - mu) * rstd * w0.w + b0.w);
    o1.x = f2b((a1.x - mu) * rstd * w1.x + b1.x);
    o1.y = f2b((a1.y - mu) * rstd * w1.y + b1.y);
    o1.z = f2b((a1.z - mu) * rstd * w1.z + b1.z);
    o1.w = f2b((a1.w - mu) * rstd * w1.w + b1.w);
    ushort4* orow = (ushort4*)(out + (size_t)row * HIDN);
    orow[tid] = o0; orow[tid + 256] = o1;
}

// ---------------- GEMM: C[M,N] = A[M,K] @ Bw[N,K]^T  (bf16 in, fp32 acc) ----------------
// 256x256 tile, 512 threads = 8 waves (2M x 4N), per-wave 128x64 output.
// Deep pipeline: 4-deep circular LDS buffer of BK=32 slabs (4 x 32KB = 128KB).
//   - slab t consumed in 2 phases (mh=0 rows, mh=1 rows), 16 MFMA each, setprio(1) around cluster
//   - slab t+3 staged during slab t's phases (A-half in phase A, B-half in phase B);
//     its buffer held slab t-1, whose last read precedes the end-of-phase-B(t-1) barrier -> safe
//   - counted s_waitcnt vmcnt(8) once per slab (2 slabs = 8 loads stay in flight across barriers);
//     tail drains 8 -> 4 -> 0. Raw s_barrier only (no __syncthreads vmcnt(0) drain).
// LDS slab layout [256 rows][32 cols] bf16 (64B rows) is bank-uniform for the ds_read_b128
// fragment pattern (8 lanes per 16B granule across all 8 granules = BW floor) -> no swizzle.
// XCD swizzle: xcd = id&7 owns a contiguous bn chunk. Requires tiles_n % 8 == 0 (or ==8).
template <int EPI>
__global__ __launch_bounds__(512)
void gemm256(const unsigned short* __restrict__ A, const unsigned short* __restrict__ Bw,
             int M, int N, int K, int tiles_n, float scale,
             const float* __restrict__ bias, const float* __restrict__ resf,
             const unsigned short* __restrict__ aux,
             float* __restrict__ outf, unsigned short* __restrict__ outb) {
    __shared__ unsigned short lds[4][2][8192];   // [buf][A|B][256*32]
    int tid = threadIdx.x;
    int wave = tid >> 6, lane = tid & 63;
    int lrow = lane & 15, quad = lane >> 4;
    int wm = wave >> 2, wn = wave & 3;
    int nchunk = tiles_n >> 3;
    int xcd = blockIdx.x & 7;
    int pxi = blockIdx.x >> 3;
    int bn = xcd * nchunk + pxi % nchunk;
    int bm = pxi / nchunk;

    f32x4 acc[8][4];
#pragma unroll
    for (int i = 0; i < 8; i++)
#pragma unroll
        for (int j = 0; j < 4; j++) acc[i][j] = f32x4{0.f, 0.f, 0.f, 0.f};

    // staging geometry: 8 waves cover 128 rows per issue; issue 1 adds +128 rows.
    int srow = wave * 16 + (lane >> 2);          // 0..127
    int scol = (lane & 3) * 8;
    const unsigned short* Ag = A + (size_t)(bm * 256 + srow) * K + scol;
    const unsigned short* Bg = Bw + (size_t)(bn * 256 + srow) * K + scol;
    const int NT = K >> 5;                        // BK=32 slabs

    auto stage = [&](int slab, int part) {
        const unsigned short* g = part ? Bg : Ag;
        unsigned short* lb = &lds[slab & 3][part][wave * 512];
        size_t koff = (size_t)slab << 5;
        gload16(g + koff, lb);
        gload16(g + koff + (size_t)128 * K, lb + 4096);
    };

    // prologue: slabs 0..2 in flight, wait slab 0 landed (vmcnt 8 = slabs 1,2 outstanding)
    stage(0, 0); stage(0, 1);
    stage(1, 0); stage(1, 1);
    stage(2, 0); stage(2, 1);
    asm volatile("s_waitcnt vmcnt(8)" ::: "memory");
    __builtin_amdgcn_s_barrier();
    asm volatile("" ::: "memory");

#pragma unroll 1
    for (int t = 0; t < NT; ++t) {
        const unsigned short* Abuf = &lds[t & 3][0][0];
        const unsigned short* Bbuf = &lds[t & 3][1][0];
        bf16x8 bfr[4], afr[4];
        // ---- phase A: rows wm*128 + [0,64) ----
#pragma unroll
        for (int ni = 0; ni < 4; ni++)
            bfr[ni] = *(const bf16x8*)&Bbuf[(wn * 64 + ni * 16 + lrow) * 32 + quad * 8];
#pragma unroll
        for (int mi = 0; mi < 4; mi++)
            afr[mi] = *(const bf16x8*)&Abuf[(wm * 128 + mi * 16 + lrow) * 32 + quad * 8];
        if (t + 3 < NT) stage(t + 3, 0);
        __builtin_amdgcn_s_barrier();
        asm volatile("s_waitcnt lgkmcnt(0)" ::: "memory");
        __builtin_amdgcn_s_setprio(1);
#pragma unroll
        for (int mi = 0; mi < 4; mi++)
#pragma unroll
            for (int ni = 0; ni < 4; ni++)
                acc[mi][ni] = __builtin_amdgcn_mfma_f32_16x16x32_bf16(afr[mi], bfr[ni], acc[mi][ni], 0, 0, 0);
        __builtin_amdgcn_s_setprio(0);
        __builtin_amdgcn_s_barrier();
        asm volatile("" ::: "memory");
        // ---- phase B: rows wm*128 + [64,128), B frags reused from registers ----
#pragma unroll
        for (int mi = 0; mi < 4; mi++)
            afr[mi] = *(const bf16x8*)&Abuf[(wm * 128 + 64 + mi * 16 + lrow) * 32 + quad * 8];
        if (t + 3 < NT) {
            stage(t + 3, 1);
            asm volatile("s_waitcnt vmcnt(8)" ::: "memory");   // slab t+1 landed; t+2,t+3 in flight
        } else if (t + 2 < NT) {
            asm volatile("s_waitcnt vmcnt(4)" ::: "memory");   // t = NT-3: slab t+1 landed
        } else if (t + 1 < NT) {
            asm volatile("s_waitcnt vmcnt(0)" ::: "memory");   // t = NT-2: last slab landed
        }
        __builtin_amdgcn_s_barrier();
        asm volatile("s_waitcnt lgkmcnt(0)" ::: "memory");
        __builtin_amdgcn_s_setprio(1);
#pragma unroll
        for (int mi = 0; mi < 4; mi++)
#pragma unroll
            for (int ni = 0; ni < 4; ni++)
                acc[4 + mi][ni] = __builtin_amdgcn_mfma_f32_16x16x32_bf16(afr[mi], bfr[ni], acc[4 + mi][ni], 0, 0, 0);
        __builtin_amdgcn_s_setprio(0);
        __builtin_amdgcn_s_barrier();
        asm volatile("" ::: "memory");
    }

    // epilogue
    int row0 = bm * 256 + wm * 128, col0 = bn * 256 + wn * 64;
#pragma unroll
    for (int mi8 = 0; mi8 < 8; mi8++) {
        int rbase = row0 + (mi8 >> 2) * 64 + (mi8 & 3) * 16 + quad * 4;
#pragma unroll
        for (int ni = 0; ni < 4; ni++) {
            int c = col0 + ni * 16 + lrow;
#pragma unroll
            for (int r = 0; r < 4; r++) {
                size_t idx = (size_t)(rbase + r) * N + c;
                float vv = acc[mi8][ni][r];
                if constexpr (EPI == 0) {
                    outb[idx] = f2b(vv * scale);
                } else if constexpr (EPI == 1) {
                    outf[idx] = vv + resf[idx];
                } else if constexpr (EPI == 2) {
                    outb[idx] = f2b(vv + bias[c]);
                } else if constexpr (EPI == 3) {
                    float av = b2f(aux[idx]);
                    float sl = av / (1.f + __expf(-av));
                    outb[idx] = f2b(sl * vv);
                } else if constexpr (EPI == 4) {
                    outf[idx] = vv + bias[c] + resf[idx];
                } else if constexpr (EPI == 5) {
                    outb[idx] = f2b(vv * (c < HIDN ? scale : 1.0f));
                }
            }
        }
    }
    (void)M;
}

// ---------------- Flash attention (causal), packed bf16 qkv [B,S,6144], bf16 out ----------------
// BM=64 (critical-path-optimal), BN=64. grid (bh=32, qt=32 reversed heavy-first).
// 2 barriers/tile: P roundtrip through wave-private LDS needs only lgkmcnt(0).
__global__ __launch_bounds__(256)
void attn_kernel(const unsigned short* __restrict__ qkv, unsigned short* __restrict__ o) {
    int bh = blockIdx.x;            // 0..31
    int qt = 31 - blockIdx.y;       // heavy tiles first
    int b = bh >> 4, h = bh & 15;
    int tid = threadIdx.x, wave = tid >> 6, lane = tid & 63;
    int lrow = lane & 15, quad = lane >> 4;
    int q0 = qt * 64;
    size_t base = ((size_t)b * SEQ) * QKVN + h * 128;
    const unsigned short* qp0 = qkv + base;
    const unsigned short* kp0 = qkv + base + HIDN;
    const unsigned short* vp0 = qkv + base + 2 * HIDN;
    size_t obase = ((size_t)b * SEQ) * HIDN + h * 128;

    __shared__ unsigned short Ksm[64 * 136];    // [key][d], pad 128->136
    __shared__ unsigned short VTsm[128 * 72];   // [d][key], pad 64->72
    __shared__ unsigned short Psm[4 * 16 * 72]; // per-wave P tile [16][72]

    bf16x8 qf[4];
    {
        const unsigned short* qp = qp0 + (size_t)(q0 + wave * 16 + lrow) * QKVN + quad * 8;
#pragma unroll
        for (int kc = 0; kc < 4; kc++) qf[kc] = *(const bf16x8*)(qp + kc * 32);
    }

    f32x4 oacc[8];
#pragma unroll
    for (int i = 0; i < 8; i++) oacc[i] = f32x4{0.f, 0.f, 0.f, 0.f};
    float m_run[4], l_run[4];
    int rowg[4];
#pragma unroll
    for (int r = 0; r < 4; r++) {
        m_run[r] = -1e30f; l_run[r] = 0.f;
        rowg[r] = q0 + wave * 16 + quad * 4 + r;
    }

    for (int kt = 0; kt <= qt; ++kt) {
        // stage K tile [64][128] -> Ksm
        {
            int r = tid >> 2, cc = (tid & 3) * 32;
            const uint4* src = (const uint4*)(kp0 + (size_t)(kt * 64 + r) * QKVN + cc);
            uint4* dst = (uint4*)&Ksm[r * 136 + cc];
            dst[0] = src[0]; dst[1] = src[1]; dst[2] = src[2]; dst[3] = src[3];
        }
        // stage V tile transposed -> VTsm[d][key]
        {
            int kv = (tid >> 3) * 2, d0 = (tid & 7) * 16;
            const unsigned short* vp = vp0 + (size_t)(kt * 64 + kv) * QKVN + d0;
            unsigned short va[16], vb[16];
            *(uint4*)&va[0] = ((const uint4*)vp)[0];
            *(uint4*)&va[8] = ((const uint4*)vp)[1];
            *(uint4*)&vb[0] = ((const uint4*)(vp + QKVN))[0];
            *(uint4*)&vb[8] = ((const uint4*)(vp + QKVN))[1];
#pragma unroll
            for (int i = 0; i < 16; i++) {
                unsigned pair = (unsigned)va[i] | ((unsigned)vb[i] << 16);
                *(unsigned*)&VTsm[(d0 + i) * 72 + kv] = pair;
            }
        }
        __syncthreads();

        // S = Q K^T  (scale pre-folded into q)
        f32x4 sacc[4];
#pragma unroll
        for (int ns = 0; ns < 4; ns++) sacc[ns] = f32x4{0.f, 0.f, 0.f, 0.f};
#pragma unroll
        for (int ns = 0; ns < 4; ns++) {
            const unsigned short* kb = &Ksm[(ns * 16 + lrow) * 136 + quad * 8];
#pragma unroll
            for (int kc = 0; kc < 4; kc++) {
                bf16x8 kf = *(const bf16x8*)(kb + kc * 32);
                sacc[ns] = __builtin_amdgcn_mfma_f32_16x16x32_bf16(qf[kc], kf, sacc[ns], 0, 0, 0);
            }
        }
        // causal mask
#pragma unroll
        for (int ns = 0; ns < 4; ns++) {
            int colg = kt * 64 + ns * 16 + lrow;
#pragma unroll
            for (int r = 0; r < 4; r++)
                if (colg > rowg[r]) sacc[ns][r] = -1e30f;
        }
        // online softmax
        float mnew[4], alpha[4], rsum[4];
#pragma unroll
        for (int r = 0; r < 4; r++) {
            float mv = fmaxf(fmaxf(sacc[0][r], sacc[1][r]), fmaxf(sacc[2][r], sacc[3][r]));
#pragma unroll
            for (int off = 1; off < 16; off <<= 1) mv = fmaxf(mv, __shfl_xor(mv, off));
            mnew[r] = fmaxf(m_run[r], mv);
            alpha[r] = __expf(m_run[r] - mnew[r]);
            rsum[r] = 0.f;
        }
#pragma unroll
        for (int ns = 0; ns < 4; ns++)
#pragma unroll
            for (int r = 0; r < 4; r++) {
                float p = __expf(sacc[ns][r] - mnew[r]);
                sacc[ns][r] = p;
                rsum[r] += p;
            }
#pragma unroll
        for (int r = 0; r < 4; r++) {
#pragma unroll
            for (int off = 1; off < 16; off <<= 1) rsum[r] += __shfl_xor(rsum[r], off);
            l_run[r] = l_run[r] * alpha[r] + rsum[r];
            m_run[r] = mnew[r];
        }
#pragma unroll
        for (int nc = 0; nc < 8; nc++)
#pragma unroll
            for (int r = 0; r < 4; r++) oacc[nc][r] *= alpha[r];

        // P: C-layout -> wave-private LDS -> A-layout (lgkmcnt only, no block barrier)
        unsigned short* pw = &Psm[wave * 16 * 72];
#pragma unroll
        for (int ns = 0; ns < 4; ns++)
#pragma unroll
            for (int r = 0; r < 4; r++)
                pw[(quad * 4 + r) * 72 + ns * 16 + lrow] = f2b(sacc[ns][r]);
        asm volatile("s_waitcnt lgkmcnt(0)" ::: "memory");
        bf16x8 pf[2];
#pragma unroll
        for (int kc = 0; kc < 2; kc++)
            pf[kc] = *(const bf16x8*)&pw[lrow * 72 + kc * 32 + quad * 8];
        // O += P V
#pragma unroll
        for (int nc = 0; nc < 8; nc++) {
#pragma unroll
            for (int kc = 0; kc < 2; kc++) {
                bf16x8 vf = *(const bf16x8*)&VTsm[(nc * 16 + lrow) * 72 + kc * 32 + quad * 8];
                oacc[nc] = __builtin_amdgcn_mfma_f32_16x16x32_bf16(pf[kc], vf, oacc[nc], 0, 0, 0);
            }
        }
        __syncthreads();
    }

    // write O
    float inv[4];
#pragma unroll
    for (int r = 0; r < 4; r++) inv[r] = 1.f / l_run[r];
#pragma unroll
    for (int nc = 0; nc < 8; nc++) {
#pragma unroll
        for (int r = 0; r < 4; r++) {
            int srow = q0 + wave * 16 + quad * 4 + r;
            o[obase + (size_t)srow * HIDN + nc * 16 + lrow] = f2b(oacc[nc][r] * inv[r]);
        }
    }
}

// ---------------- launcher ----------------
// Workspace map (peak 224 MB):
//   [0,128)  bf16 weights (one contiguous convert dst):
//            qkv packed 0-24 ([6144,2048]), o 24-32, w1 32-64, wg 64-96, w2 96-128
//   [128,192) a1/ff (in-place SwiGLU) -- aliases hbuf/qkvb (dead by then)
//            hbuf 128-144, qkvb 144-192 ([4096][6144])
//   [192,208) attnb ; [208,224) h2
//   x1 (fp32 residual) lives in d_out (EPI1/EPI4 single-touch RMW-safe).
extern "C" void kernel_launch(void* const* d_in, const int* in_sizes, int n_in,
                              void* d_out, int out_size, void* d_ws, size_t ws_size,
                              hipStream_t stream) {
    const float* x    = (const float*)d_in[0];
    const float* ln1w = (const float*)d_in[2];
    const float* ln1b = (const float*)d_in[3];
    const float* qw   = (const float*)d_in[4];
    const float* kw   = (const float*)d_in[5];
    const float* vw   = (const float*)d_in[6];
    const float* ow   = (const float*)d_in[7];
    const float* ln2w = (const float*)d_in[8];
    const float* ln2b = (const float*)d_in[9];
    const float* w1w  = (const float*)d_in[10];
    const float* w1bias = (const float*)d_in[11];
    const float* wgw  = (const float*)d_in[12];
    const float* w2w  = (const float*)d_in[13];
    const float* w2bias = (const float*)d_in[14];
    float* out = (float*)d_out;

    char* ws = (char*)d_ws;
    const size_t MB = 1ull << 20;
    unsigned short* wall  = (unsigned short*)(ws + 0 * MB);
    unsigned short* qkvwb = (unsigned short*)(ws + 0 * MB);
    unsigned short* owb  = (unsigned short*)(ws + 24 * MB);
    unsigned short* w1wb = (unsigned short*)(ws + 32 * MB);
    unsigned short* wgwb = (unsigned short*)(ws + 64 * MB);
    unsigned short* w2wb = (unsigned short*)(ws + 96 * MB);
    unsigned short* a1   = (unsigned short*)(ws + 128 * MB);
    unsigned short* hbuf = (unsigned short*)(ws + 128 * MB);
    unsigned short* qkvb = (unsigned short*)(ws + 144 * MB);
    unsigned short* attnb= (unsigned short*)(ws + 192 * MB);
    unsigned short* h2   = (unsigned short*)(ws + 208 * MB);
    float*          x1   = out;

    // one merged weight convert (16M float4s)
    convall_kernel<<<65536, 256, 0, stream>>>(qw, kw, vw, ow, w1w, wgw, w2w, wall);

    // LN1
    ln_kernel<<<NROWS, 256, 0, stream>>>(x, ln1w, ln1b, hbuf);

    const float qscale = 0.08838834764831845f; // 1/sqrt(128), folded into Q
    // fused QKV projection: [4096,2048] x [6144,2048]^T -> [4096,6144]
    gemm256<5><<<dim3(16 * 24), 512, 0, stream>>>(hbuf, qkvwb, NROWS, QKVN, HIDN, 24, qscale,
                                                  nullptr, nullptr, nullptr, nullptr, qkvb);
    // attention
    attn_kernel<<<dim3(32, 32), 256, 0, stream>>>(qkvb, attnb);
    // O-proj + residual -> x1 (fp32, = d_out)
    gemm256<1><<<dim3(16 * 8), 512, 0, stream>>>(attnb, owb, NROWS, HIDN, HIDN, 8, 1.0f,
                                                 nullptr, x, nullptr, x1, nullptr);
    // LN2
    ln_kernel<<<NROWS, 256, 0, stream>>>(x1, ln2w, ln2b, h2);
    // FFN: W1+b1 -> a1 ; WG fused silu(a1)*acc -> a1 (in-place) ; W2+b2+res -> out
    gemm256<2><<<dim3(16 * 32), 512, 0, stream>>>(h2, w1wb, NROWS, FFND, HIDN, 32, 1.0f,
                                                  w1bias, nullptr, nullptr, nullptr, a1);
    gemm256<3><<<dim3(16 * 32), 512, 0, stream>>>(h2, wgwb, NROWS, FFND, HIDN, 32, 1.0f,
                                                  nullptr, nullptr, a1, nullptr, a1);
    gemm256<4><<<dim3(16 * 8), 512, 0, stream>>>(a1, w2wb, NROWS, HIDN, FFND, 8, 1.0f,
                                                 w2bias, x1, nullptr, out, nullptr);
    (void)in_sizes; (void)n_in; (void)out_size; (void)ws_size;
}

// Round 2
// 1091.105 us; speedup vs baseline: 1.0549x; 1.0549x over previous
//
#include <hip/hip_runtime.h>
#include <cstdint>
#include <cstddef>

#define HIDN 2048
#define NROWS 4096   // B*S
#define FFND 8192
#define SEQ 2048
#define QKVN 6144    // packed q|k|v row width

typedef __attribute__((ext_vector_type(8))) __bf16 bf16x8;
typedef __attribute__((ext_vector_type(4))) float f32x4;

__device__ __forceinline__ unsigned short f2b(float f) {
    union { float f; unsigned u; } v; v.f = f;
    unsigned r = v.u + 0x7fffu + ((v.u >> 16) & 1u);
    return (unsigned short)(r >> 16);
}
__device__ __forceinline__ float b2f(unsigned short h) {
    union { unsigned u; float f; } v; v.u = ((unsigned)h) << 16; return v.f;
}
__device__ __forceinline__ void gload16(const void* g, void* lds) {
    __builtin_amdgcn_global_load_lds(
        (const __attribute__((address_space(1))) void*)g,
        (__attribute__((address_space(3))) void*)lds, 16, 0, 0);
}

// ---------------- merged fp32 -> bf16 weight convert (dst contiguous in ws) ----------------
__global__ __launch_bounds__(256) void convall_kernel(
    const float* __restrict__ s0, const float* __restrict__ s1,
    const float* __restrict__ s2, const float* __restrict__ s3,
    const float* __restrict__ s4, const float* __restrict__ s5,
    const float* __restrict__ s6, unsigned short* __restrict__ dst) {
    const int M1 = 1 << 20;
    int i = blockIdx.x * 256 + threadIdx.x;   // < 16M guaranteed by grid
    const float* src; int rel;
    if      (i <  1 * M1) { src = s0; rel = i;          }
    else if (i <  2 * M1) { src = s1; rel = i - 1 * M1; }
    else if (i <  3 * M1) { src = s2; rel = i - 2 * M1; }
    else if (i <  4 * M1) { src = s3; rel = i - 3 * M1; }
    else if (i <  8 * M1) { src = s4; rel = i - 4 * M1; }
    else if (i < 12 * M1) { src = s5; rel = i - 8 * M1; }
    else                  { src = s6; rel = i - 12 * M1; }
    float4 v = ((const float4*)src)[rel];
    ushort4 o;
    o.x = f2b(v.x); o.y = f2b(v.y); o.z = f2b(v.z); o.w = f2b(v.w);
    ((ushort4*)dst)[i] = o;
}

// ---------------- LayerNorm: fp32 in -> bf16 out, one block per 2048-row ----------------
__global__ __launch_bounds__(256) void ln_kernel(const float* __restrict__ x,
                                                 const float* __restrict__ w,
                                                 const float* __restrict__ b,
                                                 unsigned short* __restrict__ out) {
    int row = blockIdx.x, tid = threadIdx.x;
    const float4* xr = (const float4*)(x + (size_t)row * HIDN);
    float4 a0 = xr[tid], a1 = xr[tid + 256];
    float s  = a0.x + a0.y + a0.z + a0.w + a1.x + a1.y + a1.z + a1.w;
    float s2 = a0.x*a0.x + a0.y*a0.y + a0.z*a0.z + a0.w*a0.w
             + a1.x*a1.x + a1.y*a1.y + a1.z*a1.z + a1.w*a1.w;
#pragma unroll
    for (int i = 1; i < 64; i <<= 1) { s += __shfl_xor(s, i); s2 += __shfl_xor(s2, i); }
    __shared__ float red[8];
    if ((tid & 63) == 0) { red[tid >> 6] = s; red[4 + (tid >> 6)] = s2; }
    __syncthreads();
    s  = red[0] + red[1] + red[2] + red[3];
    s2 = red[4] + red[5] + red[6] + red[7];
    float mu  = s * (1.0f / HIDN);
    float var = s2 * (1.0f / HIDN) - mu * mu;
    float rstd = rsqrtf(var + 1e-5f);
    const float4* wv = (const float4*)w;
    const float4* bv = (const float4*)b;
    float4 w0 = wv[tid], w1 = wv[tid + 256], b0 = bv[tid], b1 = bv[tid + 256];
    ushort4 o0, o1;
    o0.x = f2b((a0.x - mu) * rstd * w0.x + b0.x);
    o0.y = f2b((a0.y - mu) * rstd * w0.y + b0.y);
    o0.z = f2b((a0.z - mu) * rstd * w0.z + b0.z);
    o0.w = f2b((a0.w - mu) * rstd * w0.w + b0.w);
    o1.x = f2b((a1.x - mu) * rstd * w1.x + b1.x);
    o1.y = f2b((a1.y - mu) * rstd * w1.y + b1.y);
    o1.z = f2b((a1.z - mu) * rstd * w1.z + b1.z);
    o1.w = f2b((a1.w - mu) * rstd * w1.w + b1.w);
    ushort4* orow = (ushort4*)(out + (size_t)row * HIDN);
    orow[tid] = o0; orow[tid + 256] = o1;
}

// ---------------- GEMM: C[M,N] = A[M,K] @ Bw[N,K]^T  (bf16 in, fp32 acc) ----------------
// 256x256 tile, 512 threads = 8 waves (2M x 4N), per-wave 128x64 output. BK=64.
// Faithful 8-phase port (m201 template, derived waits):
//   phase p of K-tile v computes m-frags {2p-2,2p-1} x all 4 n-frags x kk{0,1} = 16 MFMA.
//   B-frags (8 ds_read_b128) hoisted to phase 1 -> B LDS region dead after ph1.
//   A quarter-regions die per phase; A staged as interleaved halves:
//     halfA = rows {0-63,128-191} (dead after ph2), halfB = rows {64-127,192-255} (ph4).
//   Stage schedule (1 half-tile = 2 gload_lds dwordx4/thread per phase):
//     ph1: A-halfB(v+1) -> buf[v+1&1]   (that region dead since ph4(v-1))
//     ph2: B-half0(v+2) -> buf[v&1]     (B(v) dead after ph1(v))
//     ph3: B-half1(v+2) -> buf[v&1]
//     ph4: A-halfA(v+2) -> buf[v&1]     (dead after ph2(v))
//   vmcnt(6) once per K-tile at ph4: covers through ph1's issue = all of v+1; 3 half-tiles
//   (6 loads) stay in flight across barriers. Tail: vmcnt(0) only at v=NT-2. 2 raw barriers/phase.
// T2 swizzle: fragment reads at 128B row stride are 16-way conflicts; byte ^= (row&7)<<4
// makes the granule index (kk*4+quad)^(lrow&7) -> exactly 2 lanes/slot (conflict-free floor).
// Write side: linear LDS dest + pre-permuted global column ((lane&7)^(lane>>3))*8 (rule 21);
// coalescing unchanged (same 128B segments, lanes permuted within).
template <int EPI>
__global__ __launch_bounds__(512)
void gemm256(const unsigned short* __restrict__ A, const unsigned short* __restrict__ Bw,
             int M, int N, int K, int tiles_n, float scale,
             const float* __restrict__ bias, const float* __restrict__ resf,
             const unsigned short* __restrict__ aux,
             float* __restrict__ outf, unsigned short* __restrict__ outb) {
    __shared__ __align__(16) unsigned short Al[2][256 * 64];
    __shared__ __align__(16) unsigned short Bl[2][256 * 64];
    const int tid = threadIdx.x;
    const int wave = tid >> 6, lane = tid & 63;
    const int lrow = lane & 15, quad = lane >> 4;
    const int wm = wave >> 2, wn = wave & 3;
    const int nchunk = tiles_n >> 3;
    const int xcd = blockIdx.x & 7;
    const int pxi = blockIdx.x >> 3;
    const int bn = xcd * nchunk + pxi % nchunk;
    const int bm = pxi / nchunk;

    f32x4 acc[8][4];
#pragma unroll
    for (int i = 0; i < 8; i++)
#pragma unroll
        for (int j = 0; j < 4; j++) acc[i][j] = f32x4{0.f, 0.f, 0.f, 0.f};

    // staging lane constants
    const int lr8 = lane >> 3;                 // row within 8-row span
    const int colperm = (((lane & 7) ^ lr8) << 3);   // pre-swizzled global col (elements)
    const int NT = K >> 6;

    const unsigned short* Abase = A + (size_t)(bm * 256) * K;
    const unsigned short* Bbase = Bw + (size_t)(bn * 256) * K;

    auto stageA = [&](int bufi, int hr, int kt) {
#pragma unroll
        for (int j = 0; j < 2; j++) {
            int ss = wave * 2 + j;                                   // 0..15
            int rowbase = hr * 64 + (ss & 7) * 8 + (ss >> 3) * 128;  // interleaved halves
            const unsigned short* g = Abase + (size_t)(rowbase + lr8) * K + kt * 64 + colperm;
            gload16(g, &Al[bufi][rowbase * 64]);
        }
    };
    auto stageB = [&](int bufi, int hr, int kt) {
#pragma unroll
        for (int j = 0; j < 2; j++) {
            int ss = wave * 2 + j;
            int rowbase = hr * 128 + ss * 8;                         // contiguous halves
            const unsigned short* g = Bbase + (size_t)(rowbase + lr8) * K + kt * 64 + colperm;
            gload16(g, &Bl[bufi][rowbase * 64]);
        }
    };
    auto ldA = [&](int bufi, int mf, int kk) -> bf16x8 {
        int row = wm * 128 + mf * 16 + lrow;
        int off = row * 64 + ((((kk << 2) | quad) ^ (lrow & 7)) << 3);
        return *(const bf16x8*)&Al[bufi][off];
    };
    auto ldB = [&](int bufi, int nf, int kk) -> bf16x8 {
        int row = wn * 64 + nf * 16 + lrow;
        int off = row * 64 + ((((kk << 2) | quad) ^ (lrow & 7)) << 3);
        return *(const bf16x8*)&Bl[bufi][off];
    };

    // prologue: K-tile 0 complete + 3 half-tiles of K-tile 1 in flight
    stageB(0, 0, 0); stageB(0, 1, 0); stageA(0, 0, 0); stageA(0, 1, 0);
    if (NT > 1) {
        stageB(1, 0, 1); stageB(1, 1, 1); stageA(1, 0, 1);
        asm volatile("s_waitcnt vmcnt(6)" ::: "memory");
    } else {
        asm volatile("s_waitcnt vmcnt(0)" ::: "memory");
    }
    __builtin_amdgcn_s_barrier();

    bf16x8 bfr[4][2], afr[2][2];
#pragma unroll 1
    for (int v = 0; v < NT; ++v) {
        const int cb = v & 1, nb = cb ^ 1;
        // ---------------- phase 1: mf 0,1 (12 ds_reads) ----------------
#pragma unroll
        for (int nf = 0; nf < 4; nf++) { bfr[nf][0] = ldB(cb, nf, 0); bfr[nf][1] = ldB(cb, nf, 1); }
        afr[0][0] = ldA(cb, 0, 0); afr[0][1] = ldA(cb, 0, 1);
        afr[1][0] = ldA(cb, 1, 0); afr[1][1] = ldA(cb, 1, 1);
        if (v + 1 < NT) stageA(nb, 1, v + 1);
        asm volatile("" ::: "memory");
        __builtin_amdgcn_s_barrier();
        asm volatile("s_waitcnt lgkmcnt(0)" ::: "memory");
        __builtin_amdgcn_s_setprio(1);
#pragma unroll
        for (int mi = 0; mi < 2; mi++)
#pragma unroll
            for (int nf = 0; nf < 4; nf++) {
                acc[mi][nf] = __builtin_amdgcn_mfma_f32_16x16x32_bf16(afr[mi][0], bfr[nf][0], acc[mi][nf], 0, 0, 0);
                acc[mi][nf] = __builtin_amdgcn_mfma_f32_16x16x32_bf16(afr[mi][1], bfr[nf][1], acc[mi][nf], 0, 0, 0);
            }
        __builtin_amdgcn_s_setprio(0);
        __builtin_amdgcn_s_barrier();
        // ---------------- phase 2: mf 2,3 ----------------
        afr[0][0] = ldA(cb, 2, 0); afr[0][1] = ldA(cb, 2, 1);
        afr[1][0] = ldA(cb, 3, 0); afr[1][1] = ldA(cb, 3, 1);
        if (v + 2 < NT) stageB(cb, 0, v + 2);
        asm volatile("" ::: "memory");
        __builtin_amdgcn_s_barrier();
        asm volatile("s_waitcnt lgkmcnt(0)" ::: "memory");
        __builtin_amdgcn_s_setprio(1);
#pragma unroll
        for (int mi = 0; mi < 2; mi++)
#pragma unroll
            for (int nf = 0; nf < 4; nf++) {
                acc[2 + mi][nf] = __builtin_amdgcn_mfma_f32_16x16x32_bf16(afr[mi][0], bfr[nf][0], acc[2 + mi][nf], 0, 0, 0);
                acc[2 + mi][nf] = __builtin_amdgcn_mfma_f32_16x16x32_bf16(afr[mi][1], bfr[nf][1], acc[2 + mi][nf], 0, 0, 0);
            }
        __builtin_amdgcn_s_setprio(0);
        __builtin_amdgcn_s_barrier();
        // ---------------- phase 3: mf 4,5 ----------------
        afr[0][0] = ldA(cb, 4, 0); afr[0][1] = ldA(cb, 4, 1);
        afr[1][0] = ldA(cb, 5, 0); afr[1][1] = ldA(cb, 5, 1);
        if (v + 2 < NT) stageB(cb, 1, v + 2);
        asm volatile("" ::: "memory");
        __builtin_amdgcn_s_barrier();
        asm volatile("s_waitcnt lgkmcnt(0)" ::: "memory");
        __builtin_amdgcn_s_setprio(1);
#pragma unroll
        for (int mi = 0; mi < 2; mi++)
#pragma unroll
            for (int nf = 0; nf < 4; nf++) {
                acc[4 + mi][nf] = __builtin_amdgcn_mfma_f32_16x16x32_bf16(afr[mi][0], bfr[nf][0], acc[4 + mi][nf], 0, 0, 0);
                acc[4 + mi][nf] = __builtin_amdgcn_mfma_f32_16x16x32_bf16(afr[mi][1], bfr[nf][1], acc[4 + mi][nf], 0, 0, 0);
            }
        __builtin_amdgcn_s_setprio(0);
        __builtin_amdgcn_s_barrier();
        // ---------------- phase 4: mf 6,7 + counted vmcnt ----------------
        afr[0][0] = ldA(cb, 6, 0); afr[0][1] = ldA(cb, 6, 1);
        afr[1][0] = ldA(cb, 7, 0); afr[1][1] = ldA(cb, 7, 1);
        if (v + 2 < NT) {
            stageA(cb, 0, v + 2);
            asm volatile("s_waitcnt vmcnt(6)" ::: "memory");   // all of v+1 landed; 3 half-tiles in flight
        } else if (v + 1 < NT) {
            asm volatile("s_waitcnt vmcnt(0)" ::: "memory");   // tail drain (v = NT-2)
        }
        asm volatile("" ::: "memory");
        __builtin_amdgcn_s_barrier();
        asm volatile("s_waitcnt lgkmcnt(0)" ::: "memory");
        __builtin_amdgcn_s_setprio(1);
#pragma unroll
        for (int mi = 0; mi < 2; mi++)
#pragma unroll
            for (int nf = 0; nf < 4; nf++) {
                acc[6 + mi][nf] = __builtin_amdgcn_mfma_f32_16x16x32_bf16(afr[mi][0], bfr[nf][0], acc[6 + mi][nf], 0, 0, 0);
                acc[6 + mi][nf] = __builtin_amdgcn_mfma_f32_16x16x32_bf16(afr[mi][1], bfr[nf][1], acc[6 + mi][nf], 0, 0, 0);
            }
        __builtin_amdgcn_s_setprio(0);
        __builtin_amdgcn_s_barrier();
    }

    // epilogue
    int row0 = bm * 256 + wm * 128, col0 = bn * 256 + wn * 64;
#pragma unroll
    for (int mf = 0; mf < 8; mf++) {
#pragma unroll
        for (int nf = 0; nf < 4; nf++) {
            int c = col0 + nf * 16 + lrow;
#pragma unroll
            for (int r = 0; r < 4; r++) {
                int rr = row0 + mf * 16 + quad * 4 + r;
                size_t idx = (size_t)rr * N + c;
                float vv = acc[mf][nf][r];
                if constexpr (EPI == 0) {
                    outb[idx] = f2b(vv * scale);
                } else if constexpr (EPI == 1) {
                    outf[idx] = vv + resf[idx];
                } else if constexpr (EPI == 2) {
                    outb[idx] = f2b(vv + bias[c]);
                } else if constexpr (EPI == 3) {
                    float av = b2f(aux[idx]);
                    float sl = av / (1.f + __expf(-av));
                    outb[idx] = f2b(sl * vv);
                } else if constexpr (EPI == 4) {
                    outf[idx] = vv + bias[c] + resf[idx];
                } else if constexpr (EPI == 5) {
                    outb[idx] = f2b(vv * (c < HIDN ? scale : 1.0f));
                }
            }
        }
    }
    (void)M;
}

// ---------------- Flash attention (causal), packed bf16 qkv [B,S,6144], bf16 out ----------------
__global__ __launch_bounds__(256)
void attn_kernel(const unsigned short* __restrict__ qkv, unsigned short* __restrict__ o) {
    int bh = blockIdx.x;            // 0..31
    int qt = 31 - blockIdx.y;       // heavy tiles first
    int b = bh >> 4, h = bh & 15;
    int tid = threadIdx.x, wave = tid >> 6, lane = tid & 63;
    int lrow = lane & 15, quad = lane >> 4;
    int q0 = qt * 64;
    size_t base = ((size_t)b * SEQ) * QKVN + h * 128;
    const unsigned short* qp0 = qkv + base;
    const unsigned short* kp0 = qkv + base + HIDN;
    const unsigned short* vp0 = qkv + base + 2 * HIDN;
    size_t obase = ((size_t)b * SEQ) * HIDN + h * 128;

    __shared__ unsigned short Ksm[64 * 136];    // [key][d], pad 128->136
    __shared__ unsigned short VTsm[128 * 72];   // [d][key], pad 64->72
    __shared__ unsigned short Psm[4 * 16 * 72]; // per-wave P tile [16][72]

    bf16x8 qf[4];
    {
        const unsigned short* qp = qp0 + (size_t)(q0 + wave * 16 + lrow) * QKVN + quad * 8;
#pragma unroll
        for (int kc = 0; kc < 4; kc++) qf[kc] = *(const bf16x8*)(qp + kc * 32);
    }

    f32x4 oacc[8];
#pragma unroll
    for (int i = 0; i < 8; i++) oacc[i] = f32x4{0.f, 0.f, 0.f, 0.f};
    float m_run[4], l_run[4];
    int rowg[4];
#pragma unroll
    for (int r = 0; r < 4; r++) {
        m_run[r] = -1e30f; l_run[r] = 0.f;
        rowg[r] = q0 + wave * 16 + quad * 4 + r;
    }

    for (int kt = 0; kt <= qt; ++kt) {
        // stage K tile [64][128] -> Ksm
        {
            int r = tid >> 2, cc = (tid & 3) * 32;
            const uint4* src = (const uint4*)(kp0 + (size_t)(kt * 64 + r) * QKVN + cc);
            uint4* dst = (uint4*)&Ksm[r * 136 + cc];
            dst[0] = src[0]; dst[1] = src[1]; dst[2] = src[2]; dst[3] = src[3];
        }
        // stage V tile transposed -> VTsm[d][key]
        {
            int kv = (tid >> 3) * 2, d0 = (tid & 7) * 16;
            const unsigned short* vp = vp0 + (size_t)(kt * 64 + kv) * QKVN + d0;
            unsigned short va[16], vb[16];
            *(uint4*)&va[0] = ((const uint4*)vp)[0];
            *(uint4*)&va[8] = ((const uint4*)vp)[1];
            *(uint4*)&vb[0] = ((const uint4*)(vp + QKVN))[0];
            *(uint4*)&vb[8] = ((const uint4*)(vp + QKVN))[1];
#pragma unroll
            for (int i = 0; i < 16; i++) {
                unsigned pair = (unsigned)va[i] | ((unsigned)vb[i] << 16);
                *(unsigned*)&VTsm[(d0 + i) * 72 + kv] = pair;
            }
        }
        __syncthreads();

        // S = Q K^T  (scale pre-folded into q)
        f32x4 sacc[4];
#pragma unroll
        for (int ns = 0; ns < 4; ns++) sacc[ns] = f32x4{0.f, 0.f, 0.f, 0.f};
#pragma unroll
        for (int ns = 0; ns < 4; ns++) {
            const unsigned short* kb = &Ksm[(ns * 16 + lrow) * 136 + quad * 8];
#pragma unroll
            for (int kc = 0; kc < 4; kc++) {
                bf16x8 kf = *(const bf16x8*)(kb + kc * 32);
                sacc[ns] = __builtin_amdgcn_mfma_f32_16x16x32_bf16(qf[kc], kf, sacc[ns], 0, 0, 0);
            }
        }
        // causal mask
#pragma unroll
        for (int ns = 0; ns < 4; ns++) {
            int colg = kt * 64 + ns * 16 + lrow;
#pragma unroll
            for (int r = 0; r < 4; r++)
                if (colg > rowg[r]) sacc[ns][r] = -1e30f;
        }
        // online softmax
        float mnew[4], alpha[4], rsum[4];
#pragma unroll
        for (int r = 0; r < 4; r++) {
            float mv = fmaxf(fmaxf(sacc[0][r], sacc[1][r]), fmaxf(sacc[2][r], sacc[3][r]));
#pragma unroll
            for (int off = 1; off < 16; off <<= 1) mv = fmaxf(mv, __shfl_xor(mv, off));
            mnew[r] = fmaxf(m_run[r], mv);
            alpha[r] = __expf(m_run[r] - mnew[r]);
            rsum[r] = 0.f;
        }
#pragma unroll
        for (int ns = 0; ns < 4; ns++)
#pragma unroll
            for (int r = 0; r < 4; r++) {
                float p = __expf(sacc[ns][r] - mnew[r]);
                sacc[ns][r] = p;
                rsum[r] += p;
            }
#pragma unroll
        for (int r = 0; r < 4; r++) {
#pragma unroll
            for (int off = 1; off < 16; off <<= 1) rsum[r] += __shfl_xor(rsum[r], off);
            l_run[r] = l_run[r] * alpha[r] + rsum[r];
            m_run[r] = mnew[r];
        }
#pragma unroll
        for (int nc = 0; nc < 8; nc++)
#pragma unroll
            for (int r = 0; r < 4; r++) oacc[nc][r] *= alpha[r];

        // P: C-layout -> wave-private LDS -> A-layout (lgkmcnt only, no block barrier)
        unsigned short* pw = &Psm[wave * 16 * 72];
#pragma unroll
        for (int ns = 0; ns < 4; ns++)
#pragma unroll
            for (int r = 0; r < 4; r++)
                pw[(quad * 4 + r) * 72 + ns * 16 + lrow] = f2b(sacc[ns][r]);
        asm volatile("s_waitcnt lgkmcnt(0)" ::: "memory");
        bf16x8 pf[2];
#pragma unroll
        for (int kc = 0; kc < 2; kc++)
            pf[kc] = *(const bf16x8*)&pw[lrow * 72 + kc * 32 + quad * 8];
        // O += P V
#pragma unroll
        for (int nc = 0; nc < 8; nc++) {
#pragma unroll
            for (int kc = 0; kc < 2; kc++) {
                bf16x8 vf = *(const bf16x8*)&VTsm[(nc * 16 + lrow) * 72 + kc * 32 + quad * 8];
                oacc[nc] = __builtin_amdgcn_mfma_f32_16x16x32_bf16(pf[kc], vf, oacc[nc], 0, 0, 0);
            }
        }
        __syncthreads();
    }

    // write O
    float inv[4];
#pragma unroll
    for (int r = 0; r < 4; r++) inv[r] = 1.f / l_run[r];
#pragma unroll
    for (int nc = 0; nc < 8; nc++) {
#pragma unroll
        for (int r = 0; r < 4; r++) {
            int srow = q0 + wave * 16 + quad * 4 + r;
            o[obase + (size_t)srow * HIDN + nc * 16 + lrow] = f2b(oacc[nc][r] * inv[r]);
        }
    }
}

// ---------------- launcher ----------------
// Workspace map (peak 224 MB):
//   [0,128)  bf16 weights: qkv 0-24, o 24-32, w1 32-64, wg 64-96, w2 96-128
//   [128,192) a1/ff -- aliases hbuf/qkvb ; [192,208) attnb ; [208,224) h2
//   x1 (fp32 residual) lives in d_out.
extern "C" void kernel_launch(void* const* d_in, const int* in_sizes, int n_in,
                              void* d_out, int out_size, void* d_ws, size_t ws_size,
                              hipStream_t stream) {
    const float* x    = (const float*)d_in[0];
    const float* ln1w = (const float*)d_in[2];
    const float* ln1b = (const float*)d_in[3];
    const float* qw   = (const float*)d_in[4];
    const float* kw   = (const float*)d_in[5];
    const float* vw   = (const float*)d_in[6];
    const float* ow   = (const float*)d_in[7];
    const float* ln2w = (const float*)d_in[8];
    const float* ln2b = (const float*)d_in[9];
    const float* w1w  = (const float*)d_in[10];
    const float* w1bias = (const float*)d_in[11];
    const float* wgw  = (const float*)d_in[12];
    const float* w2w  = (const float*)d_in[13];
    const float* w2bias = (const float*)d_in[14];
    float* out = (float*)d_out;

    char* ws = (char*)d_ws;
    const size_t MB = 1ull << 20;
    unsigned short* wall  = (unsigned short*)(ws + 0 * MB);
    unsigned short* qkvwb = (unsigned short*)(ws + 0 * MB);
    unsigned short* owb  = (unsigned short*)(ws + 24 * MB);
    unsigned short* w1wb = (unsigned short*)(ws + 32 * MB);
    unsigned short* wgwb = (unsigned short*)(ws + 64 * MB);
    unsigned short* w2wb = (unsigned short*)(ws + 96 * MB);
    unsigned short* a1   = (unsigned short*)(ws + 128 * MB);
    unsigned short* hbuf = (unsigned short*)(ws + 128 * MB);
    unsigned short* qkvb = (unsigned short*)(ws + 144 * MB);
    unsigned short* attnb= (unsigned short*)(ws + 192 * MB);
    unsigned short* h2   = (unsigned short*)(ws + 208 * MB);
    float*          x1   = out;

    // one merged weight convert (16M float4s)
    convall_kernel<<<65536, 256, 0, stream>>>(qw, kw, vw, ow, w1w, wgw, w2w, wall);

    // LN1
    ln_kernel<<<NROWS, 256, 0, stream>>>(x, ln1w, ln1b, hbuf);

    const float qscale = 0.08838834764831845f; // 1/sqrt(128), folded into Q
    // fused QKV projection: [4096,2048] x [6144,2048]^T -> [4096,6144]
    gemm256<5><<<dim3(16 * 24), 512, 0, stream>>>(hbuf, qkvwb, NROWS, QKVN, HIDN, 24, qscale,
                                                  nullptr, nullptr, nullptr, nullptr, qkvb);
    // attention
    attn_kernel<<<dim3(32, 32), 256, 0, stream>>>(qkvb, attnb);
    // O-proj + residual -> x1 (fp32, = d_out)
    gemm256<1><<<dim3(16 * 8), 512, 0, stream>>>(attnb, owb, NROWS, HIDN, HIDN, 8, 1.0f,
                                                 nullptr, x, nullptr, x1, nullptr);
    // LN2
    ln_kernel<<<NROWS, 256, 0, stream>>>(x1, ln2w, ln2b, h2);
    // FFN: W1+b1 -> a1 ; WG fused silu(a1)*acc -> a1 (in-place) ; W2+b2+res -> out
    gemm256<2><<<dim3(16 * 32), 512, 0, stream>>>(h2, w1wb, NROWS, FFND, HIDN, 32, 1.0f,
                                                  w1bias, nullptr, nullptr, nullptr, a1);
    gemm256<3><<<dim3(16 * 32), 512, 0, stream>>>(h2, wgwb, NROWS, FFND, HIDN, 32, 1.0f,
                                                  nullptr, nullptr, a1, nullptr, a1);
    gemm256<4><<<dim3(16 * 8), 512, 0, stream>>>(a1, w2wb, NROWS, HIDN, FFND, 8, 1.0f,
                                                 w2bias, x1, nullptr, out, nullptr);
    (void)in_sizes; (void)n_in; (void)out_size; (void)ws_size;
}